// Round 8
// baseline (469.339 us; speedup 1.0000x reference)
//
#include <hip/hip_runtime.h>
#include <cstdint>
#include <cmath>

#define IMG_H 128
#define IMG_W 128

// PROJ constants: computed in double exactly as the Python reference, then cast to f32.
constexpr double FOCAL_D = 140.0, NEAR_D = 0.1, FAR_D = 10.0;
constexpr double RIGHT_D = (IMG_W - 1.0) / 2.0 * NEAR_D / FOCAL_D;
constexpr double TOP_D   = RIGHT_D * ((double)IMG_H / (double)IMG_W);
constexpr float P00 = (float)(NEAR_D / RIGHT_D);
constexpr float P11 = (float)(NEAR_D / TOP_D);
constexpr float P22 = (float)(-(FAR_D + NEAR_D) / (FAR_D - NEAR_D));
constexpr float P32 = (float)(-2.0 * FAR_D * NEAR_D / (FAR_D - NEAR_D));

__device__ __forceinline__ unsigned long long packKey(float z, int f) {
    unsigned int zb = __float_as_uint(z);
    zb = (zb & 0x80000000u) ? ~zb : (zb | 0x80000000u);  // monotone total order
    return ((unsigned long long)zb << 32) | (unsigned int)f;
}

// ---------------- vertex transform: world -> screen (sx, sy, sz, w) ----------------
__global__ void k_vertex(const float* __restrict__ verts, const float* __restrict__ poses,
                         float4* __restrict__ vscr, int B, int N) {
#pragma clang fp contract(off)
    int id = blockIdx.x * blockDim.x + threadIdx.x;
    if (id >= B * N) return;
    int b = id / N;
    const float* v = verts + (size_t)id * 3;
    const float* P = poses + (size_t)b * 16;
    float x = v[0], y = v[1], z = v[2];
    float cp[4][4] = {
        { P[0],  P[1],  P[2],  P[3]  },
        {-P[4], -P[5], -P[6], -P[7]  },
        {-P[8], -P[9], -P[10],-P[11] },
        { P[12], P[13], P[14], P[15] }
    };
    float cam[4];
    for (int j = 0; j < 4; ++j)
        cam[j] = ((x * cp[j][0] + y * cp[j][1]) + z * cp[j][2]) + cp[j][3];
    float c0 = cam[0] * P00;
    float c1 = cam[1] * P11;
    float c2 = (cam[2] * P22) + (cam[3] * P32);
    float c3 = cam[2] * (-1.0f);
    float sx = ((c0 / c3) * 0.5f + 0.5f) * (float)IMG_W;
    float sy = (0.5f - (c1 / c3) * 0.5f) * (float)IMG_H;
    float sz = c2 / c3;
    vscr[id] = make_float4(sx, sy, sz, c3);
}

// ---------------- rasterizer: ONE WAVE PER FACE, 8x8 lane-tiles over face bbox ----------------
// z-prefilter: volatile (device-coherent) read hoisted to iteration top so its ~L2/HBM
// latency overlaps the edge math; awaited only at the final k<cur test. Volatile is
// REQUIRED: plain loads can hit a stale cross-XCD L2 line from a previous graph replay
// whose keys are smaller -> would wrongly suppress atomics (R5 failure).
__global__ __launch_bounds__(256) void k_rasterF(const int* __restrict__ faces,
                                                 const float4* __restrict__ vscr,
                                                 unsigned long long* __restrict__ keybuf,
                                                 int B, int N, int F) {
#pragma clang fp contract(off)
    int wid = __builtin_amdgcn_readfirstlane(blockIdx.x * 4 + (threadIdx.x >> 6));
    if (wid >= B * F) return;
    int b = wid / F;
    int f = wid - b * F;
    int lane = threadIdx.x & 63;

    int i0 = faces[f * 3 + 0], i1 = faces[f * 3 + 1], i2 = faces[f * 3 + 2];
    float4 v0 = vscr[(size_t)b * N + i0];
    float4 v1 = vscr[(size_t)b * N + i1];
    float4 v2 = vscr[(size_t)b * N + i2];

    // wok: reference sets ok=false if any w <= 1e-6 -> face contributes nothing
    if (!(v0.w > 1e-6f && v1.w > 1e-6f && v2.w > 1e-6f)) return;

    // edge deltas, identical expressions/order to reference
    float dx0 = v2.x - v1.x, dy0 = v2.y - v1.y;   // e0 anchor (v1)
    float dx1 = v0.x - v2.x, dy1 = v0.y - v2.y;   // e1 anchor (v2)
    float dx2 = v1.x - v0.x, dy2 = v1.y - v0.y;   // e2 anchor (v0)
    float z0 = v0.z, z1 = v1.z, z2 = v2.z;

    float minx = fminf(v0.x, fminf(v1.x, v2.x));
    float maxx = fmaxf(v0.x, fmaxf(v1.x, v2.x));
    float miny = fminf(v0.y, fminf(v1.y, v2.y));
    float maxy = fmaxf(v0.y, fmaxf(v1.y, v2.y));
    // NaN guard (reference: NaN edge fns -> inside false everywhere)
    if (!(minx <= maxx) || !(miny <= maxy)) return;
    // clamp to sane range before int conversion (huge coords from tiny w)
    minx = fmaxf(minx, -4.0f);  maxx = fminf(maxx, (float)IMG_W + 4.0f);
    miny = fmaxf(miny, -4.0f);  maxy = fminf(maxy, (float)IMG_H + 4.0f);
    // pixel index range with >=1px guard band for edge-fn rounding slack
    int xlo = max(0, (int)floorf(minx) - 1);
    int xhi = min(IMG_W - 1, (int)floorf(maxx) + 1);
    int ylo = max(0, (int)floorf(miny) - 1);
    int yhi = min(IMG_H - 1, (int)floorf(maxy) + 1);
    if (xlo > xhi || ylo > yhi) return;

    int lx = lane & 7, lyn = lane >> 3;
    unsigned long long* kb = keybuf + (size_t)b * IMG_H * IMG_W;

    for (int y0 = ylo; y0 <= yhi; y0 += 8) {
        int y = y0 + lyn;
        bool yok = (y <= yhi);
        int yc = min(y, IMG_H - 1);                  // clamped for prefilter address
        float py = (float)y + 0.5f;
        float pyd0 = py - v1.y, pyd1 = py - v2.y, pyd2 = py - v0.y;
        for (int x0 = xlo; x0 <= xhi; x0 += 8) {
            int x = x0 + lx;
            bool ok = yok && (x <= xhi);
            int xc = min(x, IMG_W - 1);
            // issue the coherent prefilter read FIRST; consumed only at the k<cur test,
            // so its latency overlaps all the edge math below.
            unsigned long long cur =
                *(const volatile unsigned long long*)&kb[(size_t)yc * IMG_W + xc];
            float px = (float)x + 0.5f;
            // bit-exact reference op order (contract off)
            float e0 = dx0 * pyd0 - dy0 * (px - v1.x);
            float e1 = dx1 * pyd1 - dy1 * (px - v2.x);
            float e2 = dx2 * pyd2 - dy2 * (px - v0.x);
            float area = (e0 + e1) + e2;
            bool okA = fabsf(area) > 1e-9f;
            float s = (area > 0.0f) ? 1.0f : ((area < 0.0f) ? -1.0f : area);
            bool inside = (e0 * s >= 0.0f) && (e1 * s >= 0.0f) && (e2 * s >= 0.0f)
                          && okA && ok;
            if (__ballot(inside)) {
                float den = okA ? area : 1.0f;
                float zpix = ((e0 * z0 + e1 * z1) + e2 * z2) / den;
                if (inside && (zpix >= -1.0f) && (zpix <= 1.0f)) {
                    unsigned long long k = packKey(zpix, f);
                    if (k < cur)
                        atomicMin(&kb[(size_t)y * IMG_W + x], k);  // fire-and-forget
                }
            }
        }
    }
}

// ---------------- shade + bilinear texture sample ----------------
__global__ void k_shade(const unsigned long long* __restrict__ keybuf,
                        const int* __restrict__ faces, const float4* __restrict__ vscr,
                        const float* __restrict__ uvmap, const float* __restrict__ tex,
                        float* __restrict__ out, int B, int N, int tside) {
#pragma clang fp contract(off)
    int id = blockIdx.x * blockDim.x + threadIdx.x;
    if (id >= B * IMG_H * IMG_W) return;
    int b = id / (IMG_H * IMG_W);
    int p = id - b * (IMG_H * IMG_W);
    int y = p / IMG_W, x = p - y * IMG_W;
    unsigned long long key = keybuf[id];
    int fid = (key == ~0ull) ? -1 : (int)(key & 0xFFFFFFFFull);
    int f = (fid < 0) ? 0 : fid;
    int i0 = faces[f * 3 + 0], i1 = faces[f * 3 + 1], i2 = faces[f * 3 + 2];
    float4 v0 = vscr[(size_t)b * N + i0];
    float4 v1 = vscr[(size_t)b * N + i1];
    float4 v2 = vscr[(size_t)b * N + i2];
    float px = (float)x + 0.5f, py = (float)y + 0.5f;
    float e0 = (v2.x - v1.x) * (py - v1.y) - (v2.y - v1.y) * (px - v1.x);
    float e1 = (v0.x - v2.x) * (py - v2.y) - (v0.y - v2.y) * (px - v2.x);
    float e2 = (v1.x - v0.x) * (py - v0.y) - (v1.y - v0.y) * (px - v0.x);
    float bw0 = e0 / v0.w, bw1 = e1 / v1.w, bw2 = e2 / v2.w;
    float den = (bw0 + bw1) + bw2;
    den = (fabsf(den) > 1e-9f) ? den : 1.0f;
    float pc0 = bw0 / den, pc1 = bw1 / den, pc2 = bw2 / den;
    float u0 = uvmap[((size_t)b * N + i0) * 2],     vv0 = uvmap[((size_t)b * N + i0) * 2 + 1];
    float u1 = uvmap[((size_t)b * N + i1) * 2],     vv1 = uvmap[((size_t)b * N + i1) * 2 + 1];
    float u2 = uvmap[((size_t)b * N + i2) * 2],     vv2 = uvmap[((size_t)b * N + i2) * 2 + 1];
    float g0 = (pc0 * 1.0f + pc1 * 1.0f) + pc2 * 1.0f;
    float g1 = (pc0 * u0 + pc1 * u1) + pc2 * u2;
    float g2 = (pc0 * vv0 + pc1 * vv1) + pc2 * vv2;
    float mask = (fid >= 0) ? 1.0f : 0.0f;
    g0 = g0 * mask; g1 = g1 * mask; g2 = g2 * mask;
    float ts = (float)tside;
    float iyf = fminf(fmaxf(g2, 0.0f), 1.0f) * ts;
    float ixf = fminf(fmaxf(g1, 0.0f), 1.0f) * ts;
    float fly = floorf(iyf), flx = floorf(ixf);
    float fy = iyf - fly, fx = ixf - flx;
    int iy = (int)fly, ix = (int)flx;
    int tmax = tside - 1;
    int iy0 = min(max(iy, 0), tmax),     iy1 = min(max(iy + 1, 0), tmax);
    int ix0 = min(max(ix, 0), tmax),     ix1 = min(max(ix + 1, 0), tmax);
    const float* tb = tex + (size_t)b * tside * tside * 3;
    const float* tl = tb + ((size_t)iy0 * tside + ix0) * 3;
    const float* tr = tb + ((size_t)iy0 * tside + ix1) * 3;
    const float* bl = tb + ((size_t)iy1 * tside + ix0) * 3;
    const float* br = tb + ((size_t)iy1 * tside + ix1) * 3;
    float omfx = 1.0f - fx, omfy = 1.0f - fy;
    float* o = out + (size_t)id * 3;
    for (int c = 0; c < 3; ++c) {
        float r = (((tl[c] * omfx) * omfy) + ((tr[c] * fx) * omfy)) + ((bl[c] * omfx) * fy);
        r = r + ((br[c] * fx) * fy);
        o[c] = r * g0;
    }
}

extern "C" void kernel_launch(void* const* d_in, const int* in_sizes, int n_in,
                              void* d_out, int out_size, void* d_ws, size_t ws_size,
                              hipStream_t stream) {
    const float* verts = (const float*)d_in[0];
    const float* uvmap = (const float*)d_in[1];
    const int*   faces = (const int*)d_in[2];
    const float* tex   = (const float*)d_in[3];
    const float* poses = (const float*)d_in[4];
    int B = in_sizes[4] / 16;
    int N = in_sizes[0] / (B * 3);
    int F = in_sizes[2] / 3;
    int texels = in_sizes[3] / (B * 3);
    int tside = (int)(sqrt((double)texels) + 0.5);

    char* ws = (char*)d_ws;
    float4* vscr = (float4*)ws;
    size_t off = (size_t)B * N * sizeof(float4);
    unsigned long long* keybuf = (unsigned long long*)(ws + off);
    size_t keybytes = (size_t)B * IMG_H * IMG_W * sizeof(unsigned long long);

    hipMemsetAsync(keybuf, 0xFF, keybytes, stream);
    k_vertex<<<(B * N + 255) / 256, 256, 0, stream>>>(verts, poses, vscr, B, N);
    int nwaves = B * F;
    k_rasterF<<<(nwaves + 3) / 4, 256, 0, stream>>>(faces, vscr, keybuf, B, N, F);
    k_shade<<<(B * IMG_H * IMG_W + 255) / 256, 256, 0, stream>>>(
        keybuf, faces, vscr, uvmap, tex, (float*)d_out, B, N, tside);
}

// Round 9
// 466.544 us; speedup vs baseline: 1.0060x; 1.0060x over previous
//
#include <hip/hip_runtime.h>
#include <cstdint>
#include <cmath>

#define IMG_H 128
#define IMG_W 128

// PROJ constants: computed in double exactly as the Python reference, then cast to f32.
constexpr double FOCAL_D = 140.0, NEAR_D = 0.1, FAR_D = 10.0;
constexpr double RIGHT_D = (IMG_W - 1.0) / 2.0 * NEAR_D / FOCAL_D;
constexpr double TOP_D   = RIGHT_D * ((double)IMG_H / (double)IMG_W);
constexpr float P00 = (float)(NEAR_D / RIGHT_D);
constexpr float P11 = (float)(NEAR_D / TOP_D);
constexpr float P22 = (float)(-(FAR_D + NEAR_D) / (FAR_D - NEAR_D));
constexpr float P32 = (float)(-2.0 * FAR_D * NEAR_D / (FAR_D - NEAR_D));

__device__ __forceinline__ unsigned long long packKey(float z, int f) {
    unsigned int zb = __float_as_uint(z);
    zb = (zb & 0x80000000u) ? ~zb : (zb | 0x80000000u);  // monotone total order
    return ((unsigned long long)zb << 32) | (unsigned int)f;
}

// ---------------- vertex transform: world -> screen (sx, sy, sz, w) ----------------
__global__ void k_vertex(const float* __restrict__ verts, const float* __restrict__ poses,
                         float4* __restrict__ vscr, int B, int N) {
#pragma clang fp contract(off)
    int id = blockIdx.x * blockDim.x + threadIdx.x;
    if (id >= B * N) return;
    int b = id / N;
    const float* v = verts + (size_t)id * 3;
    const float* P = poses + (size_t)b * 16;
    float x = v[0], y = v[1], z = v[2];
    float cp[4][4] = {
        { P[0],  P[1],  P[2],  P[3]  },
        {-P[4], -P[5], -P[6], -P[7]  },
        {-P[8], -P[9], -P[10],-P[11] },
        { P[12], P[13], P[14], P[15] }
    };
    float cam[4];
    for (int j = 0; j < 4; ++j)
        cam[j] = ((x * cp[j][0] + y * cp[j][1]) + z * cp[j][2]) + cp[j][3];
    float c0 = cam[0] * P00;
    float c1 = cam[1] * P11;
    float c2 = (cam[2] * P22) + (cam[3] * P32);
    float c3 = cam[2] * (-1.0f);
    float sx = ((c0 / c3) * 0.5f + 0.5f) * (float)IMG_W;
    float sy = (0.5f - (c1 / c3) * 0.5f) * (float)IMG_H;
    float sz = c2 / c3;
    vscr[id] = make_float4(sx, sy, sz, c3);
}

// ---------------- rasterizer: ONE WAVE PER FACE, 8x8 lane-tiles over face bbox ----------------
// z-prefilter: RELAXED AGENT-SCOPE ATOMIC LOAD. Coherent at the device coherence point
// (bypasses L1 and per-XCD L2 -> immune to cross-replay stale lines, the R5 failure),
// but relaxed ordering -> no per-iteration vmcnt drain (the R4/R7 volatile serialization).
// Stale-within-launch values are always >= actual (keys only decrease from the 0xFF memset),
// so filtering can only admit extra atomics, never suppress a needed one.
__global__ __launch_bounds__(256) void k_rasterF(const int* __restrict__ faces,
                                                 const float4* __restrict__ vscr,
                                                 unsigned long long* __restrict__ keybuf,
                                                 int B, int N, int F) {
#pragma clang fp contract(off)
    int wid = __builtin_amdgcn_readfirstlane(blockIdx.x * 4 + (threadIdx.x >> 6));
    if (wid >= B * F) return;
    int b = wid / F;
    int f = wid - b * F;
    int lane = threadIdx.x & 63;

    int i0 = faces[f * 3 + 0], i1 = faces[f * 3 + 1], i2 = faces[f * 3 + 2];
    float4 v0 = vscr[(size_t)b * N + i0];
    float4 v1 = vscr[(size_t)b * N + i1];
    float4 v2 = vscr[(size_t)b * N + i2];

    // wok: reference sets ok=false if any w <= 1e-6 -> face contributes nothing
    if (!(v0.w > 1e-6f && v1.w > 1e-6f && v2.w > 1e-6f)) return;

    // edge deltas, identical expressions/order to reference
    float dx0 = v2.x - v1.x, dy0 = v2.y - v1.y;   // e0 anchor (v1)
    float dx1 = v0.x - v2.x, dy1 = v0.y - v2.y;   // e1 anchor (v2)
    float dx2 = v1.x - v0.x, dy2 = v1.y - v0.y;   // e2 anchor (v0)
    float z0 = v0.z, z1 = v1.z, z2 = v2.z;

    float minx = fminf(v0.x, fminf(v1.x, v2.x));
    float maxx = fmaxf(v0.x, fmaxf(v1.x, v2.x));
    float miny = fminf(v0.y, fminf(v1.y, v2.y));
    float maxy = fmaxf(v0.y, fmaxf(v1.y, v2.y));
    // NaN guard (reference: NaN edge fns -> inside false everywhere)
    if (!(minx <= maxx) || !(miny <= maxy)) return;
    // clamp to sane range before int conversion (huge coords from tiny w)
    minx = fmaxf(minx, -4.0f);  maxx = fminf(maxx, (float)IMG_W + 4.0f);
    miny = fmaxf(miny, -4.0f);  maxy = fminf(maxy, (float)IMG_H + 4.0f);
    // pixel index range with >=1px guard band for edge-fn rounding slack
    int xlo = max(0, (int)floorf(minx) - 1);
    int xhi = min(IMG_W - 1, (int)floorf(maxx) + 1);
    int ylo = max(0, (int)floorf(miny) - 1);
    int yhi = min(IMG_H - 1, (int)floorf(maxy) + 1);
    if (xlo > xhi || ylo > yhi) return;

    int lx = lane & 7, lyn = lane >> 3;
    unsigned long long* kb = keybuf + (size_t)b * IMG_H * IMG_W;

    for (int y0 = ylo; y0 <= yhi; y0 += 8) {
        int y = y0 + lyn;
        bool yok = (y <= yhi);
        int yc = min(y, IMG_H - 1);                  // clamped for prefilter address
        float py = (float)y + 0.5f;
        float pyd0 = py - v1.y, pyd1 = py - v2.y, pyd2 = py - v0.y;
        for (int x0 = xlo; x0 <= xhi; x0 += 8) {
            int x = x0 + lx;
            bool ok = yok && (x <= xhi);
            int xc = min(x, IMG_W - 1);
            // coherent, non-serializing prefilter read; issued first, consumed last
            unsigned long long cur = __hip_atomic_load(
                &kb[(size_t)yc * IMG_W + xc], __ATOMIC_RELAXED, __HIP_MEMORY_SCOPE_AGENT);
            float px = (float)x + 0.5f;
            // bit-exact reference op order (contract off)
            float e0 = dx0 * pyd0 - dy0 * (px - v1.x);
            float e1 = dx1 * pyd1 - dy1 * (px - v2.x);
            float e2 = dx2 * pyd2 - dy2 * (px - v0.x);
            float area = (e0 + e1) + e2;
            bool okA = fabsf(area) > 1e-9f;
            float s = (area > 0.0f) ? 1.0f : ((area < 0.0f) ? -1.0f : area);
            bool inside = (e0 * s >= 0.0f) && (e1 * s >= 0.0f) && (e2 * s >= 0.0f)
                          && okA && ok;
            if (__ballot(inside)) {
                float den = okA ? area : 1.0f;
                float zpix = ((e0 * z0 + e1 * z1) + e2 * z2) / den;
                if (inside && (zpix >= -1.0f) && (zpix <= 1.0f)) {
                    unsigned long long k = packKey(zpix, f);
                    if (k < cur)
                        atomicMin(&kb[(size_t)y * IMG_W + x], k);  // fire-and-forget
                }
            }
        }
    }
}

// ---------------- shade + bilinear texture sample ----------------
__global__ void k_shade(const unsigned long long* __restrict__ keybuf,
                        const int* __restrict__ faces, const float4* __restrict__ vscr,
                        const float* __restrict__ uvmap, const float* __restrict__ tex,
                        float* __restrict__ out, int B, int N, int tside) {
#pragma clang fp contract(off)
    int id = blockIdx.x * blockDim.x + threadIdx.x;
    if (id >= B * IMG_H * IMG_W) return;
    int b = id / (IMG_H * IMG_W);
    int p = id - b * (IMG_H * IMG_W);
    int y = p / IMG_W, x = p - y * IMG_W;
    unsigned long long key = keybuf[id];
    int fid = (key == ~0ull) ? -1 : (int)(key & 0xFFFFFFFFull);
    int f = (fid < 0) ? 0 : fid;
    int i0 = faces[f * 3 + 0], i1 = faces[f * 3 + 1], i2 = faces[f * 3 + 2];
    float4 v0 = vscr[(size_t)b * N + i0];
    float4 v1 = vscr[(size_t)b * N + i1];
    float4 v2 = vscr[(size_t)b * N + i2];
    float px = (float)x + 0.5f, py = (float)y + 0.5f;
    float e0 = (v2.x - v1.x) * (py - v1.y) - (v2.y - v1.y) * (px - v1.x);
    float e1 = (v0.x - v2.x) * (py - v2.y) - (v0.y - v2.y) * (px - v2.x);
    float e2 = (v1.x - v0.x) * (py - v0.y) - (v1.y - v0.y) * (px - v0.x);
    float bw0 = e0 / v0.w, bw1 = e1 / v1.w, bw2 = e2 / v2.w;
    float den = (bw0 + bw1) + bw2;
    den = (fabsf(den) > 1e-9f) ? den : 1.0f;
    float pc0 = bw0 / den, pc1 = bw1 / den, pc2 = bw2 / den;
    float u0 = uvmap[((size_t)b * N + i0) * 2],     vv0 = uvmap[((size_t)b * N + i0) * 2 + 1];
    float u1 = uvmap[((size_t)b * N + i1) * 2],     vv1 = uvmap[((size_t)b * N + i1) * 2 + 1];
    float u2 = uvmap[((size_t)b * N + i2) * 2],     vv2 = uvmap[((size_t)b * N + i2) * 2 + 1];
    float g0 = (pc0 * 1.0f + pc1 * 1.0f) + pc2 * 1.0f;
    float g1 = (pc0 * u0 + pc1 * u1) + pc2 * u2;
    float g2 = (pc0 * vv0 + pc1 * vv1) + pc2 * vv2;
    float mask = (fid >= 0) ? 1.0f : 0.0f;
    g0 = g0 * mask; g1 = g1 * mask; g2 = g2 * mask;
    float ts = (float)tside;
    float iyf = fminf(fmaxf(g2, 0.0f), 1.0f) * ts;
    float ixf = fminf(fmaxf(g1, 0.0f), 1.0f) * ts;
    float fly = floorf(iyf), flx = floorf(ixf);
    float fy = iyf - fly, fx = ixf - flx;
    int iy = (int)fly, ix = (int)flx;
    int tmax = tside - 1;
    int iy0 = min(max(iy, 0), tmax),     iy1 = min(max(iy + 1, 0), tmax);
    int ix0 = min(max(ix, 0), tmax),     ix1 = min(max(ix + 1, 0), tmax);
    const float* tb = tex + (size_t)b * tside * tside * 3;
    const float* tl = tb + ((size_t)iy0 * tside + ix0) * 3;
    const float* tr = tb + ((size_t)iy0 * tside + ix1) * 3;
    const float* bl = tb + ((size_t)iy1 * tside + ix0) * 3;
    const float* br = tb + ((size_t)iy1 * tside + ix1) * 3;
    float omfx = 1.0f - fx, omfy = 1.0f - fy;
    float* o = out + (size_t)id * 3;
    for (int c = 0; c < 3; ++c) {
        float r = (((tl[c] * omfx) * omfy) + ((tr[c] * fx) * omfy)) + ((bl[c] * omfx) * fy);
        r = r + ((br[c] * fx) * fy);
        o[c] = r * g0;
    }
}

extern "C" void kernel_launch(void* const* d_in, const int* in_sizes, int n_in,
                              void* d_out, int out_size, void* d_ws, size_t ws_size,
                              hipStream_t stream) {
    const float* verts = (const float*)d_in[0];
    const float* uvmap = (const float*)d_in[1];
    const int*   faces = (const int*)d_in[2];
    const float* tex   = (const float*)d_in[3];
    const float* poses = (const float*)d_in[4];
    int B = in_sizes[4] / 16;
    int N = in_sizes[0] / (B * 3);
    int F = in_sizes[2] / 3;
    int texels = in_sizes[3] / (B * 3);
    int tside = (int)(sqrt((double)texels) + 0.5);

    char* ws = (char*)d_ws;
    float4* vscr = (float4*)ws;
    size_t off = (size_t)B * N * sizeof(float4);
    unsigned long long* keybuf = (unsigned long long*)(ws + off);
    size_t keybytes = (size_t)B * IMG_H * IMG_W * sizeof(unsigned long long);

    hipMemsetAsync(keybuf, 0xFF, keybytes, stream);
    k_vertex<<<(B * N + 255) / 256, 256, 0, stream>>>(verts, poses, vscr, B, N);
    int nwaves = B * F;
    k_rasterF<<<(nwaves + 3) / 4, 256, 0, stream>>>(faces, vscr, keybuf, B, N, F);
    k_shade<<<(B * IMG_H * IMG_W + 255) / 256, 256, 0, stream>>>(
        keybuf, faces, vscr, uvmap, tex, (float*)d_out, B, N, tside);
}

// Round 10
// 433.950 us; speedup vs baseline: 1.0816x; 1.0751x over previous
//
#include <hip/hip_runtime.h>
#include <cstdint>
#include <cmath>

#define IMG_H 128
#define IMG_W 128

// PROJ constants: computed in double exactly as the Python reference, then cast to f32.
constexpr double FOCAL_D = 140.0, NEAR_D = 0.1, FAR_D = 10.0;
constexpr double RIGHT_D = (IMG_W - 1.0) / 2.0 * NEAR_D / FOCAL_D;
constexpr double TOP_D   = RIGHT_D * ((double)IMG_H / (double)IMG_W);
constexpr float P00 = (float)(NEAR_D / RIGHT_D);
constexpr float P11 = (float)(NEAR_D / TOP_D);
constexpr float P22 = (float)(-(FAR_D + NEAR_D) / (FAR_D - NEAR_D));
constexpr float P32 = (float)(-2.0 * FAR_D * NEAR_D / (FAR_D - NEAR_D));

__device__ __forceinline__ unsigned long long packKey(float z, int f) {
    unsigned int zb = __float_as_uint(z);
    zb = (zb & 0x80000000u) ? ~zb : (zb | 0x80000000u);  // monotone total order
    return ((unsigned long long)zb << 32) | (unsigned int)f;
}

// ---------------- vertex transform: world -> screen (sx, sy, sz, w) ----------------
__global__ void k_vertex(const float* __restrict__ verts, const float* __restrict__ poses,
                         float4* __restrict__ vscr, int B, int N) {
#pragma clang fp contract(off)
    int id = blockIdx.x * blockDim.x + threadIdx.x;
    if (id >= B * N) return;
    int b = id / N;
    const float* v = verts + (size_t)id * 3;
    const float* P = poses + (size_t)b * 16;
    float x = v[0], y = v[1], z = v[2];
    float cp[4][4] = {
        { P[0],  P[1],  P[2],  P[3]  },
        {-P[4], -P[5], -P[6], -P[7]  },
        {-P[8], -P[9], -P[10],-P[11] },
        { P[12], P[13], P[14], P[15] }
    };
    float cam[4];
    for (int j = 0; j < 4; ++j)
        cam[j] = ((x * cp[j][0] + y * cp[j][1]) + z * cp[j][2]) + cp[j][3];
    float c0 = cam[0] * P00;
    float c1 = cam[1] * P11;
    float c2 = (cam[2] * P22) + (cam[3] * P32);
    float c3 = cam[2] * (-1.0f);
    float sx = ((c0 / c3) * 0.5f + 0.5f) * (float)IMG_W;
    float sy = (0.5f - (c1 / c3) * 0.5f) * (float)IMG_H;
    float sz = c2 / c3;
    vscr[id] = make_float4(sx, sy, sz, c3);
}

// ---------------- rasterizer: ONE WAVE PER FACE, 8x8 lane-tiles over face bbox ----------------
// NO z-prefilter reads (R4/R7/R8 post-mortems: coherent keybuf reads cost 75-150us to save
// ~7.7M fire-and-forget atomics that cost only a few us). Inner loop is pure VALU +
// unconditional atomicMin for inside lanes. No keybuf loads -> replay-safe by construction.
__global__ __launch_bounds__(256) void k_rasterF(const int* __restrict__ faces,
                                                 const float4* __restrict__ vscr,
                                                 unsigned long long* __restrict__ keybuf,
                                                 int B, int N, int F) {
#pragma clang fp contract(off)
    int wid = __builtin_amdgcn_readfirstlane(blockIdx.x * 4 + (threadIdx.x >> 6));
    if (wid >= B * F) return;
    int b = wid / F;
    int f = wid - b * F;
    int lane = threadIdx.x & 63;

    int i0 = faces[f * 3 + 0], i1 = faces[f * 3 + 1], i2 = faces[f * 3 + 2];
    float4 v0 = vscr[(size_t)b * N + i0];
    float4 v1 = vscr[(size_t)b * N + i1];
    float4 v2 = vscr[(size_t)b * N + i2];

    // wok: reference sets ok=false if any w <= 1e-6 -> face contributes nothing
    if (!(v0.w > 1e-6f && v1.w > 1e-6f && v2.w > 1e-6f)) return;

    // edge deltas, identical expressions/order to reference
    float dx0 = v2.x - v1.x, dy0 = v2.y - v1.y;   // e0 anchor (v1)
    float dx1 = v0.x - v2.x, dy1 = v0.y - v2.y;   // e1 anchor (v2)
    float dx2 = v1.x - v0.x, dy2 = v1.y - v0.y;   // e2 anchor (v0)
    float z0 = v0.z, z1 = v1.z, z2 = v2.z;

    float minx = fminf(v0.x, fminf(v1.x, v2.x));
    float maxx = fmaxf(v0.x, fmaxf(v1.x, v2.x));
    float miny = fminf(v0.y, fminf(v1.y, v2.y));
    float maxy = fmaxf(v0.y, fmaxf(v1.y, v2.y));
    // NaN guard (reference: NaN edge fns -> inside false everywhere)
    if (!(minx <= maxx) || !(miny <= maxy)) return;
    // clamp to sane range before int conversion (huge coords from tiny w)
    minx = fmaxf(minx, -4.0f);  maxx = fminf(maxx, (float)IMG_W + 4.0f);
    miny = fmaxf(miny, -4.0f);  maxy = fminf(maxy, (float)IMG_H + 4.0f);
    // pixel index range with >=1px guard band for edge-fn rounding slack
    int xlo = max(0, (int)floorf(minx) - 1);
    int xhi = min(IMG_W - 1, (int)floorf(maxx) + 1);
    int ylo = max(0, (int)floorf(miny) - 1);
    int yhi = min(IMG_H - 1, (int)floorf(maxy) + 1);
    if (xlo > xhi || ylo > yhi) return;

    int lx = lane & 7, lyn = lane >> 3;
    unsigned long long* kb = keybuf + (size_t)b * IMG_H * IMG_W;

    for (int y0 = ylo; y0 <= yhi; y0 += 8) {
        int y = y0 + lyn;
        bool yok = (y <= yhi);
        float py = (float)y + 0.5f;
        float pyd0 = py - v1.y, pyd1 = py - v2.y, pyd2 = py - v0.y;
        for (int x0 = xlo; x0 <= xhi; x0 += 8) {
            int x = x0 + lx;
            bool ok = yok && (x <= xhi);
            float px = (float)x + 0.5f;
            // bit-exact reference op order (contract off)
            float e0 = dx0 * pyd0 - dy0 * (px - v1.x);
            float e1 = dx1 * pyd1 - dy1 * (px - v2.x);
            float e2 = dx2 * pyd2 - dy2 * (px - v0.x);
            float area = (e0 + e1) + e2;
            bool okA = fabsf(area) > 1e-9f;
            float s = (area > 0.0f) ? 1.0f : ((area < 0.0f) ? -1.0f : area);
            bool inside = (e0 * s >= 0.0f) && (e1 * s >= 0.0f) && (e2 * s >= 0.0f)
                          && okA && ok;
            if (__ballot(inside)) {
                float den = okA ? area : 1.0f;
                float zpix = ((e0 * z0 + e1 * z1) + e2 * z2) / den;
                if (inside && (zpix >= -1.0f) && (zpix <= 1.0f)) {
                    // fire-and-forget device-scope atomic; no return -> no wait
                    atomicMin(&kb[(size_t)y * IMG_W + x], packKey(zpix, f));
                }
            }
        }
    }
}

// ---------------- shade + bilinear texture sample ----------------
__global__ void k_shade(const unsigned long long* __restrict__ keybuf,
                        const int* __restrict__ faces, const float4* __restrict__ vscr,
                        const float* __restrict__ uvmap, const float* __restrict__ tex,
                        float* __restrict__ out, int B, int N, int tside) {
#pragma clang fp contract(off)
    int id = blockIdx.x * blockDim.x + threadIdx.x;
    if (id >= B * IMG_H * IMG_W) return;
    int b = id / (IMG_H * IMG_W);
    int p = id - b * (IMG_H * IMG_W);
    int y = p / IMG_W, x = p - y * IMG_W;
    unsigned long long key = keybuf[id];
    int fid = (key == ~0ull) ? -1 : (int)(key & 0xFFFFFFFFull);
    int f = (fid < 0) ? 0 : fid;
    int i0 = faces[f * 3 + 0], i1 = faces[f * 3 + 1], i2 = faces[f * 3 + 2];
    float4 v0 = vscr[(size_t)b * N + i0];
    float4 v1 = vscr[(size_t)b * N + i1];
    float4 v2 = vscr[(size_t)b * N + i2];
    float px = (float)x + 0.5f, py = (float)y + 0.5f;
    float e0 = (v2.x - v1.x) * (py - v1.y) - (v2.y - v1.y) * (px - v1.x);
    float e1 = (v0.x - v2.x) * (py - v2.y) - (v0.y - v2.y) * (px - v2.x);
    float e2 = (v1.x - v0.x) * (py - v0.y) - (v1.y - v0.y) * (px - v0.x);
    float bw0 = e0 / v0.w, bw1 = e1 / v1.w, bw2 = e2 / v2.w;
    float den = (bw0 + bw1) + bw2;
    den = (fabsf(den) > 1e-9f) ? den : 1.0f;
    float pc0 = bw0 / den, pc1 = bw1 / den, pc2 = bw2 / den;
    float u0 = uvmap[((size_t)b * N + i0) * 2],     vv0 = uvmap[((size_t)b * N + i0) * 2 + 1];
    float u1 = uvmap[((size_t)b * N + i1) * 2],     vv1 = uvmap[((size_t)b * N + i1) * 2 + 1];
    float u2 = uvmap[((size_t)b * N + i2) * 2],     vv2 = uvmap[((size_t)b * N + i2) * 2 + 1];
    float g0 = (pc0 * 1.0f + pc1 * 1.0f) + pc2 * 1.0f;
    float g1 = (pc0 * u0 + pc1 * u1) + pc2 * u2;
    float g2 = (pc0 * vv0 + pc1 * vv1) + pc2 * vv2;
    float mask = (fid >= 0) ? 1.0f : 0.0f;
    g0 = g0 * mask; g1 = g1 * mask; g2 = g2 * mask;
    float ts = (float)tside;
    float iyf = fminf(fmaxf(g2, 0.0f), 1.0f) * ts;
    float ixf = fminf(fmaxf(g1, 0.0f), 1.0f) * ts;
    float fly = floorf(iyf), flx = floorf(ixf);
    float fy = iyf - fly, fx = ixf - flx;
    int iy = (int)fly, ix = (int)flx;
    int tmax = tside - 1;
    int iy0 = min(max(iy, 0), tmax),     iy1 = min(max(iy + 1, 0), tmax);
    int ix0 = min(max(ix, 0), tmax),     ix1 = min(max(ix + 1, 0), tmax);
    const float* tb = tex + (size_t)b * tside * tside * 3;
    const float* tl = tb + ((size_t)iy0 * tside + ix0) * 3;
    const float* tr = tb + ((size_t)iy0 * tside + ix1) * 3;
    const float* bl = tb + ((size_t)iy1 * tside + ix0) * 3;
    const float* br = tb + ((size_t)iy1 * tside + ix1) * 3;
    float omfx = 1.0f - fx, omfy = 1.0f - fy;
    float* o = out + (size_t)id * 3;
    for (int c = 0; c < 3; ++c) {
        float r = (((tl[c] * omfx) * omfy) + ((tr[c] * fx) * omfy)) + ((bl[c] * omfx) * fy);
        r = r + ((br[c] * fx) * fy);
        o[c] = r * g0;
    }
}

extern "C" void kernel_launch(void* const* d_in, const int* in_sizes, int n_in,
                              void* d_out, int out_size, void* d_ws, size_t ws_size,
                              hipStream_t stream) {
    const float* verts = (const float*)d_in[0];
    const float* uvmap = (const float*)d_in[1];
    const int*   faces = (const int*)d_in[2];
    const float* tex   = (const float*)d_in[3];
    const float* poses = (const float*)d_in[4];
    int B = in_sizes[4] / 16;
    int N = in_sizes[0] / (B * 3);
    int F = in_sizes[2] / 3;
    int texels = in_sizes[3] / (B * 3);
    int tside = (int)(sqrt((double)texels) + 0.5);

    char* ws = (char*)d_ws;
    float4* vscr = (float4*)ws;
    size_t off = (size_t)B * N * sizeof(float4);
    unsigned long long* keybuf = (unsigned long long*)(ws + off);
    size_t keybytes = (size_t)B * IMG_H * IMG_W * sizeof(unsigned long long);

    hipMemsetAsync(keybuf, 0xFF, keybytes, stream);
    k_vertex<<<(B * N + 255) / 256, 256, 0, stream>>>(verts, poses, vscr, B, N);
    int nwaves = B * F;
    k_rasterF<<<(nwaves + 3) / 4, 256, 0, stream>>>(faces, vscr, keybuf, B, N, F);
    k_shade<<<(B * IMG_H * IMG_W + 255) / 256, 256, 0, stream>>>(
        keybuf, faces, vscr, uvmap, tex, (float*)d_out, B, N, tside);
}